// Round 3
// baseline (228.329 us; speedup 1.0000x reference)
//
#include <hip/hip_runtime.h>

// NURBS surface eval, two-stage separable form, quad-V stage 2.
//   Stage 1 (per block = batch b x 8 U-rows): u-contraction into LDS:
//     rows[u][n] = sum_l Nu[U,l] * ctrl[b, iu[U,l], n, :]   (float4, n=0..63)
//   Stage 2: thread owns 4 consecutive V (one quad) and 4 u-rows.
//     Key fact: iv[V,0..3] = span(V)-3 .. span(V), and span varies by <=1
//     across 4 consecutive V (knot spacing ~8.5 output steps). So per u-row
//     read 5 contiguous float4s from LDS and select the 4-wide window per V
//     with cndmask (d = iv[V].x - iv[V0].x, read from the table, in {0,1}).
//   DS reads/thread: 20 (was 64). Stores: 3x dwordx4 per u (48 B contiguous).

#define OUTDIM 512
#define CTRL_N 64
#define TU 8

__global__ __launch_bounds__(256) void surf_eval_kernel(
    const float* __restrict__ ctrl,   // [B,64,64,4]
    const float* __restrict__ Nu,     // [512,4]
    const float* __restrict__ Nv,     // [512,4]
    const int*   __restrict__ iu,     // [512,4]
    const int*   __restrict__ iv,     // [512,4]
    float*       __restrict__ out)    // [B,512,512,3]
{
    __shared__ float4 rows[TU * CTRL_N];   // 8 KB

    const int blk = blockIdx.x;
    const int b  = blk >> 6;               // 0..63
    const int U0 = (blk & 63) * TU;        // 0,8,...,504
    const int t  = threadIdx.x;

    // ---------- stage 1: u-contraction into LDS ----------
    {
        const int u  = t >> 5;             // 0..7
        const int n0 = t & 31;             // 0..31 (+32 for second point)
        const int U  = U0 + u;
        const float4 nu  = *(const float4*)(Nu + U * 4);
        const int4   iu4 = *(const int4*)(iu + U * 4);
        const float* cb = ctrl + (size_t)b * (64 * 64 * 4);
        const float* r0 = cb + (size_t)iu4.x * (CTRL_N * 4);
        const float* r1 = cb + (size_t)iu4.y * (CTRL_N * 4);
        const float* r2 = cb + (size_t)iu4.z * (CTRL_N * 4);
        const float* r3 = cb + (size_t)iu4.w * (CTRL_N * 4);

#pragma unroll
        for (int k = 0; k < 2; ++k) {
            const int n = n0 + 32 * k;
            const float4 p0 = *(const float4*)(r0 + n * 4);
            const float4 p1 = *(const float4*)(r1 + n * 4);
            const float4 p2 = *(const float4*)(r2 + n * 4);
            const float4 p3 = *(const float4*)(r3 + n * 4);
            float4 acc;
            acc.x = nu.x * p0.x + nu.y * p1.x + nu.z * p2.x + nu.w * p3.x;
            acc.y = nu.x * p0.y + nu.y * p1.y + nu.z * p2.y + nu.w * p3.y;
            acc.z = nu.x * p0.z + nu.y * p1.z + nu.z * p2.z + nu.w * p3.z;
            acc.w = nu.x * p0.w + nu.y * p1.w + nu.z * p2.w + nu.w * p3.w;
            rows[u * CTRL_N + n] = acc;
        }
    }
    __syncthreads();

    // ---------- stage 2: quad-V contraction from LDS ----------
    const int q  = t & 127;                // quad index, V0 = 4q
    const int V0 = q * 4;
    const int u0 = (t >> 7) * 4;           // 0 or 4: this thread's 4 u-rows

    // Per-V basis weights (4 float4) and window offsets d[j] in {0,1}.
    float4 nv[4];
    int    d[4];
    const int s0 = iv[(size_t)V0 * 4];     // iv[V0].x = span(V0)-3
#pragma unroll
    for (int j = 0; j < 4; ++j) {
        nv[j] = *(const float4*)(Nv + (V0 + j) * 4);
        d[j]  = iv[(size_t)(V0 + j) * 4] - s0;   // 0 or 1
    }

    const size_t obase = ((size_t)b * OUTDIM + U0) * OUTDIM;

#pragma unroll
    for (int uu = 0; uu < 4; ++uu) {
        const int u = u0 + uu;
        const float4* ru = rows + u * CTRL_N + s0;

        // 5 contiguous float4s cover both candidate windows.
        float4 qb0 = ru[0], qb1 = ru[1], qb2 = ru[2], qb3 = ru[3], qb4 = ru[4];

        float px[4], py[4], pz[4];
#pragma unroll
        for (int j = 0; j < 4; ++j) {
            const bool sh = (d[j] != 0);
            const float4 w0 = sh ? qb1 : qb0;
            const float4 w1 = sh ? qb2 : qb1;
            const float4 w2 = sh ? qb3 : qb2;
            const float4 w3 = sh ? qb4 : qb3;
            const float4 n4 = nv[j];
            float sx = n4.x * w0.x + n4.y * w1.x + n4.z * w2.x + n4.w * w3.x;
            float sy = n4.x * w0.y + n4.y * w1.y + n4.z * w2.y + n4.w * w3.y;
            float sz = n4.x * w0.z + n4.y * w1.z + n4.z * w2.z + n4.w * w3.z;
            float sw = n4.x * w0.w + n4.y * w1.w + n4.z * w2.w + n4.w * w3.w;
            const float inv = __builtin_amdgcn_rcpf(sw);
            px[j] = sx * inv;
            py[j] = sy * inv;
            pz[j] = sz * inv;
        }

        // Pack 4 points (12 floats) into 3 float4 stores, 16B-aligned.
        float* o = out + (obase + (size_t)u * OUTDIM + V0) * 3;
        float4 s0v = {px[0], py[0], pz[0], px[1]};
        float4 s1v = {py[1], pz[1], px[2], py[2]};
        float4 s2v = {pz[2], px[3], py[3], pz[3]};
        ((float4*)o)[0] = s0v;
        ((float4*)o)[1] = s1v;
        ((float4*)o)[2] = s2v;
    }
}

extern "C" void kernel_launch(void* const* d_in, const int* in_sizes, int n_in,
                              void* d_out, int out_size, void* d_ws, size_t ws_size,
                              hipStream_t stream) {
    const float* ctrl = (const float*)d_in[0];
    const float* Nu   = (const float*)d_in[1];
    const float* Nv   = (const float*)d_in[2];
    const int*   iu   = (const int*)d_in[3];
    const int*   iv   = (const int*)d_in[4];
    float* out = (float*)d_out;

    // grid: 64 batches x 64 U-tiles (of 8 rows) = 4096 blocks of 256 threads
    const int nblocks = 64 * (OUTDIM / TU);
    surf_eval_kernel<<<nblocks, 256, 0, stream>>>(ctrl, Nu, Nv, iu, iv, out);
}

// Round 4
// 226.096 us; speedup vs baseline: 1.0099x; 1.0099x over previous
//
#include <hip/hip_runtime.h>

// NURBS surface eval, two-stage separable form, quad-V stage 2 with
// hoisted 5-tap window weights.
//   Stage 1 (per block = batch b x 8 U-rows): u-contraction into LDS:
//     rows[u][n] = sum_l Nu[U,l] * ctrl[b, iu[U,l], n, :]   (float4, n=0..63)
//   Stage 2: thread owns 4 consecutive V (a quad) x 4 u-rows.
//     iv[V,0..3] = span(V)-3..span(V); span shifts by <=1 across a quad
//     (verified: R3 passed with this assumption read from the table).
//     Build per-V 5-tap weights ONCE:
//       w5 = d==0 ? {n0,n1,n2,n3,0} : {0,n0,n1,n2,n3}
//     Inner loop: 5 contiguous ds_read_b128 + pure 5-tap dot (no selects).
//   DS reads/thread: 20 (R2 had 64); inner-loop VALU: 20 fma/output (R2: 16,
//   R3: 16 fma + 16 cndmask). Stores: 3x dwordx4 per u-row (48 B/thread).

#define OUTDIM 512
#define CTRL_N 64
#define TU 8

__global__ __launch_bounds__(256) void surf_eval_kernel(
    const float* __restrict__ ctrl,   // [B,64,64,4]
    const float* __restrict__ Nu,     // [512,4]
    const float* __restrict__ Nv,     // [512,4]
    const int*   __restrict__ iu,     // [512,4]
    const int*   __restrict__ iv,     // [512,4]
    float*       __restrict__ out)    // [B,512,512,3]
{
    __shared__ float4 rows[TU * CTRL_N];   // 8 KB

    const int blk = blockIdx.x;
    const int b  = blk >> 6;               // 0..63
    const int U0 = (blk & 63) * TU;        // 0,8,...,504
    const int t  = threadIdx.x;

    // ---------- stage 1: u-contraction into LDS ----------
    {
        const int u  = t >> 5;             // 0..7
        const int n0 = t & 31;             // 0..31 (+32 for second point)
        const int U  = U0 + u;
        const float4 nu  = *(const float4*)(Nu + U * 4);
        const int4   iu4 = *(const int4*)(iu + U * 4);
        const float* cb = ctrl + (size_t)b * (64 * 64 * 4);
        const float* r0 = cb + (size_t)iu4.x * (CTRL_N * 4);
        const float* r1 = cb + (size_t)iu4.y * (CTRL_N * 4);
        const float* r2 = cb + (size_t)iu4.z * (CTRL_N * 4);
        const float* r3 = cb + (size_t)iu4.w * (CTRL_N * 4);

#pragma unroll
        for (int k = 0; k < 2; ++k) {
            const int n = n0 + 32 * k;
            const float4 p0 = *(const float4*)(r0 + n * 4);
            const float4 p1 = *(const float4*)(r1 + n * 4);
            const float4 p2 = *(const float4*)(r2 + n * 4);
            const float4 p3 = *(const float4*)(r3 + n * 4);
            float4 acc;
            acc.x = nu.x * p0.x + nu.y * p1.x + nu.z * p2.x + nu.w * p3.x;
            acc.y = nu.x * p0.y + nu.y * p1.y + nu.z * p2.y + nu.w * p3.y;
            acc.z = nu.x * p0.z + nu.y * p1.z + nu.z * p2.z + nu.w * p3.z;
            acc.w = nu.x * p0.w + nu.y * p1.w + nu.z * p2.w + nu.w * p3.w;
            rows[u * CTRL_N + n] = acc;
        }
    }
    __syncthreads();

    // ---------- stage 2: quad-V contraction from LDS ----------
    const int q  = t & 127;                // quad index, V0 = 4q
    const int V0 = q * 4;
    const int u0 = (t >> 7) * 4;           // 0 or 4: this thread's 4 u-rows

    // One-time: per-V 5-tap weights over the fixed window [s0 .. s0+4].
    const int s0 = iv[(size_t)V0 * 4];     // iv[V0].x = span(V0)-3
    float w5[4][5];
#pragma unroll
    for (int j = 0; j < 4; ++j) {
        const float4 n4 = *(const float4*)(Nv + (V0 + j) * 4);
        const bool sh = (iv[(size_t)(V0 + j) * 4] != s0);   // d in {0,1}
        w5[j][0] = sh ? 0.f  : n4.x;
        w5[j][1] = sh ? n4.x : n4.y;
        w5[j][2] = sh ? n4.y : n4.z;
        w5[j][3] = sh ? n4.z : n4.w;
        w5[j][4] = sh ? n4.w : 0.f;
    }

    const size_t obase = ((size_t)b * OUTDIM + U0) * OUTDIM;

#pragma unroll
    for (int uu = 0; uu < 4; ++uu) {
        const int u = u0 + uu;
        const float4* ru = rows + u * CTRL_N + s0;

        // 5 contiguous float4s cover all 4 V windows of this quad.
        const float4 q0 = ru[0], q1 = ru[1], q2 = ru[2], q3 = ru[3], q4 = ru[4];

        float px[4], py[4], pz[4];
#pragma unroll
        for (int j = 0; j < 4; ++j) {
            const float w0 = w5[j][0], w1 = w5[j][1], w2 = w5[j][2],
                        w3 = w5[j][3], w4 = w5[j][4];
            float sx = w0 * q0.x + w1 * q1.x + w2 * q2.x + w3 * q3.x + w4 * q4.x;
            float sy = w0 * q0.y + w1 * q1.y + w2 * q2.y + w3 * q3.y + w4 * q4.y;
            float sz = w0 * q0.z + w1 * q1.z + w2 * q2.z + w3 * q3.z + w4 * q4.z;
            float sw = w0 * q0.w + w1 * q1.w + w2 * q2.w + w3 * q3.w + w4 * q4.w;
            const float inv = __builtin_amdgcn_rcpf(sw);
            px[j] = sx * inv;
            py[j] = sy * inv;
            pz[j] = sz * inv;
        }

        // Pack 4 points (12 floats) into 3 float4 stores, 16B-aligned.
        float* o = out + (obase + (size_t)u * OUTDIM + V0) * 3;
        float4 s0v = {px[0], py[0], pz[0], px[1]};
        float4 s1v = {py[1], pz[1], px[2], py[2]};
        float4 s2v = {pz[2], px[3], py[3], pz[3]};
        ((float4*)o)[0] = s0v;
        ((float4*)o)[1] = s1v;
        ((float4*)o)[2] = s2v;
    }
}

extern "C" void kernel_launch(void* const* d_in, const int* in_sizes, int n_in,
                              void* d_out, int out_size, void* d_ws, size_t ws_size,
                              hipStream_t stream) {
    const float* ctrl = (const float*)d_in[0];
    const float* Nu   = (const float*)d_in[1];
    const float* Nv   = (const float*)d_in[2];
    const int*   iu   = (const int*)d_in[3];
    const int*   iv   = (const int*)d_in[4];
    float* out = (float*)d_out;

    // grid: 64 batches x 64 U-tiles (of 8 rows) = 4096 blocks of 256 threads
    const int nblocks = 64 * (OUTDIM / TU);
    surf_eval_kernel<<<nblocks, 256, 0, stream>>>(ctrl, Nu, Nv, iu, iv, out);
}